// Round 1
// baseline (247.974 us; speedup 1.0000x reference)
//
#include <hip/hip_runtime.h>

// GPT-2 attention block, B=4 S=2048 D=1024 H=16 DH=64, f32 in/out.
// All matmuls in bf16 MFMA (v_mfma_f32_16x16x32_bf16), f32 accumulate.
// Assumed fragment layouts (gfx950):
//   A: lane l elem b -> A[l&15][8*(l>>4)+b]      (K-consecutive-8)
//   B: lane l elem b -> B[8*(l>>4)+b][l&15]
//   C/D: lane l reg r -> D[4*(l>>4)+r][l&15]     (verified, learn_hip m89)

typedef short  s8v   __attribute__((ext_vector_type(8)));  // 8 bf16 payload (16B)
typedef float  f32x4 __attribute__((ext_vector_type(4)));
typedef unsigned short u16;
typedef u16    u16x4 __attribute__((ext_vector_type(4)));

__device__ __forceinline__ u16 f2b(float f) {
  union { float f; unsigned u; } v; v.f = f;
  unsigned r = v.u + 0x7FFFu + ((v.u >> 16) & 1u);   // RNE
  return (u16)(r >> 16);
}

// ---------------- f32 -> bf16 elementwise (x4 vectorized) ----------------
__global__ __launch_bounds__(256) void k_cvt(const float* __restrict__ in,
                                             u16* __restrict__ out, int n4) {
  int t = blockIdx.x * 256 + threadIdx.x;
  if (t < n4) {
    f32x4 f = ((const f32x4*)in)[t];
    u16x4 o;
    o[0] = f2b(f[0]); o[1] = f2b(f[1]); o[2] = f2b(f[2]); o[3] = f2b(f[3]);
    ((u16x4*)out)[t] = o;
  }
}

// ---------------- f32 [R][C] -> bf16 [C][R] transpose ----------------
__global__ __launch_bounds__(256) void k_tr(const float* __restrict__ in,
                                            u16* __restrict__ out, int R, int C) {
  __shared__ float tile[32][33];
  int c0 = blockIdx.x * 32, r0 = blockIdx.y * 32;
  int tx = threadIdx.x, ty = threadIdx.y;
#pragma unroll
  for (int j = 0; j < 4; j++)
    tile[ty + j * 8][tx] = in[(size_t)(r0 + ty + j * 8) * C + c0 + tx];
  __syncthreads();
#pragma unroll
  for (int j = 0; j < 4; j++)
    out[(size_t)(c0 + ty + j * 8) * R + r0 + tx] = f2b(tile[tx][ty + j * 8]);
}

// ---------------- bf16 GEMM: C[M,N] = A[M,K] @ Bt[N,K]^T (+bias) ----------------
// 128x128 tile, BK=32, 256 threads = 4 waves, each wave 64x64 (4x4 frags).
// EPI 0: scatter to q/k/v [bh][S][64] bf16, q scaled by 0.125.  EPI 1: f32 out.
template <int EPI>
__global__ __launch_bounds__(256) void k_gemm(
    const u16* __restrict__ A, const u16* __restrict__ Bt,
    const float* __restrict__ bias,
    u16* __restrict__ qb, u16* __restrict__ kb, u16* __restrict__ vb,
    float* __restrict__ outf, int M, int N, int K) {
  __shared__ u16 lA[128 * 40];   // +8 pad: 80B row stride, 2-way-max banks
  __shared__ u16 lB[128 * 40];
  const int tid = threadIdx.x;
  const int lane = tid & 63, w = tid >> 6;
  const int wr = (w >> 1) * 64, wc = (w & 1) * 64;
  const int lr = lane & 15, lg = lane >> 4;
  const int m0 = blockIdx.y * 128, n0 = blockIdx.x * 128;

  const int srow = tid >> 1, scol = (tid & 1) * 16;
  const u16* gA = A + (size_t)(m0 + srow) * K + scol;
  const u16* gB = Bt + (size_t)(n0 + srow) * K + scol;

  f32x4 acc[4][4];
  f32x4 zz = {0.f, 0.f, 0.f, 0.f};
#pragma unroll
  for (int m = 0; m < 4; m++)
#pragma unroll
    for (int n = 0; n < 4; n++) acc[m][n] = zz;

  s8v a0 = *(const s8v*)(gA), a1 = *(const s8v*)(gA + 8);
  s8v b0 = *(const s8v*)(gB), b1 = *(const s8v*)(gB + 8);

  const int nk = K / 32;
  for (int kt = 0; kt < nk; ++kt) {
    __syncthreads();                       // prior iter frag reads done
    *(s8v*)&lA[srow * 40 + scol] = a0;
    *(s8v*)&lA[srow * 40 + scol + 8] = a1;
    *(s8v*)&lB[srow * 40 + scol] = b0;
    *(s8v*)&lB[srow * 40 + scol + 8] = b1;
    if (kt + 1 < nk) {                     // prefetch overlaps MFMA phase
      const u16* nA = gA + (kt + 1) * 32;
      const u16* nB = gB + (kt + 1) * 32;
      a0 = *(const s8v*)(nA); a1 = *(const s8v*)(nA + 8);
      b0 = *(const s8v*)(nB); b1 = *(const s8v*)(nB + 8);
    }
    __syncthreads();
    s8v af[4], bf[4];
#pragma unroll
    for (int m = 0; m < 4; m++)
      af[m] = *(const s8v*)&lA[(wr + m * 16 + lr) * 40 + 8 * lg];
#pragma unroll
    for (int n = 0; n < 4; n++)
      bf[n] = *(const s8v*)&lB[(wc + n * 16 + lr) * 40 + 8 * lg];
#pragma unroll
    for (int m = 0; m < 4; m++)
#pragma unroll
      for (int n = 0; n < 4; n++)
        acc[m][n] = __builtin_amdgcn_mfma_f32_16x16x32_bf16(af[m], bf[n], acc[m][n], 0, 0, 0);
  }

#pragma unroll
  for (int m = 0; m < 4; m++) {
#pragma unroll
    for (int n = 0; n < 4; n++) {
      const int col = n0 + wc + n * 16 + lr;
      const float bb = bias[col];
      if (EPI == 0) {
        const int which = col >> 10, d = col & 1023, h = d >> 6, dh = d & 63;
        u16* dst = which == 0 ? qb : (which == 1 ? kb : vb);
        const float sc = which == 0 ? 0.125f : 1.0f;  // fold 1/sqrt(DH) into Q
#pragma unroll
        for (int r = 0; r < 4; r++) {
          const int row = m0 + wr + m * 16 + 4 * lg + r;
          const int b = row >> 11, s = row & 2047;
          dst[(size_t)((b * 16 + h) * 2048 + s) * 64 + dh] = f2b((acc[m][n][r] + bb) * sc);
        }
      } else {
#pragma unroll
        for (int r = 0; r < 4; r++) {
          const int row = m0 + wr + m * 16 + 4 * lg + r;
          outf[(size_t)row * N + col] = acc[m][n][r] + bb;
        }
      }
    }
  }
}

// ---------------- flash attention, causal, bf16 MFMA ----------------
// grid (64 bh, 16 qt). 4 waves x 32 q-rows = QT 128. KVT = 64.
__global__ __launch_bounds__(256) void k_attn(
    const u16* __restrict__ Q, const u16* __restrict__ K,
    const u16* __restrict__ V, u16* __restrict__ O) {
  __shared__ u16 lK[64 * 72];        // [kv][dh], +8 pad
  __shared__ u16 lVt[64 * 72];       // [dh][kv], +8 pad (transposed at stage)
  __shared__ u16 lP[4 * 32 * 72];    // per-wave P [32 q][kv], +8 pad
  const int bh = blockIdx.x;
  const int qt = 15 - (int)blockIdx.y;     // big tiles launch first
  const int tid = threadIdx.x, lane = tid & 63, w = tid >> 6;
  const int lr = lane & 15, lg = lane >> 4;
  const int qbase = qt * 128 + w * 32;

  s8v qf[2][2];
#pragma unroll
  for (int m = 0; m < 2; m++)
#pragma unroll
    for (int h = 0; h < 2; h++)
      qf[m][h] = *(const s8v*)(Q + (size_t)(bh * 2048 + qbase + m * 16 + lr) * 64 + h * 32 + 8 * lg);

  f32x4 accO[2][4];
  f32x4 zz = {0.f, 0.f, 0.f, 0.f};
  float mrun[2][4], lrun[2][4];
#pragma unroll
  for (int m = 0; m < 2; m++) {
#pragma unroll
    for (int n = 0; n < 4; n++) accO[m][n] = zz;
#pragma unroll
    for (int r = 0; r < 4; r++) { mrun[m][r] = -1e30f; lrun[m][r] = 0.f; }
  }

  u16* Pw = &lP[w * (32 * 72)];
  const int sr = tid >> 2, sc = (tid & 3) * 16;
  const int ntile = 2 * qt + 2;

  for (int kvt = 0; kvt < ntile; ++kvt) {
    const int kv0 = kvt * 64;
    const u16* gk = K + (size_t)(bh * 2048 + kv0 + sr) * 64 + sc;
    const u16* gv = V + (size_t)(bh * 2048 + kv0 + sr) * 64 + sc;
    s8v k0r = *(const s8v*)gk, k1r = *(const s8v*)(gk + 8);
    s8v v0r = *(const s8v*)gv, v1r = *(const s8v*)(gv + 8);
    __syncthreads();                      // prior PV done with lK/lVt
    *(s8v*)&lK[sr * 72 + sc] = k0r;
    *(s8v*)&lK[sr * 72 + sc + 8] = k1r;
#pragma unroll
    for (int j = 0; j < 8; j++) {         // transpose V into [dh][kv]
      lVt[(sc + j) * 72 + sr] = (u16)k0r[0] * 0 + (u16)((unsigned short)v0r[j]);
      lVt[(sc + 8 + j) * 72 + sr] = (u16)((unsigned short)v1r[j]);
    }
    __syncthreads();

    const bool active = (kv0 <= qbase + 31);   // wave-uniform causal skip
    if (active) {
      // ---- QK^T: S[32 q][64 kv] per wave ----
      f32x4 st[2][4];
#pragma unroll
      for (int kvf = 0; kvf < 4; kvf++) {
        s8v kf0 = *(const s8v*)&lK[(kvf * 16 + lr) * 72 + 8 * lg];
        s8v kf1 = *(const s8v*)&lK[(kvf * 16 + lr) * 72 + 32 + 8 * lg];
#pragma unroll
        for (int m = 0; m < 2; m++) {
          f32x4 z = {0.f, 0.f, 0.f, 0.f};
          z = __builtin_amdgcn_mfma_f32_16x16x32_bf16(qf[m][0], kf0, z, 0, 0, 0);
          st[m][kvf] = __builtin_amdgcn_mfma_f32_16x16x32_bf16(qf[m][1], kf1, z, 0, 0, 0);
        }
      }
      // ---- causal mask (only near diagonal) ----
      if (kv0 + 63 > qbase) {
#pragma unroll
        for (int m = 0; m < 2; m++)
#pragma unroll
          for (int kvf = 0; kvf < 4; kvf++)
#pragma unroll
            for (int r = 0; r < 4; r++) {
              const int qq = qbase + m * 16 + 4 * lg + r;
              const int kk = kv0 + kvf * 16 + lr;
              if (kk > qq) st[m][kvf][r] = -1e9f;
            }
      }
      // ---- online softmax (row stats via 16-lane shuffle reduce) ----
      float fs[2][4];
#pragma unroll
      for (int m = 0; m < 2; m++)
#pragma unroll
        for (int r = 0; r < 4; r++) {
          float v = fmaxf(fmaxf(st[m][0][r], st[m][1][r]), fmaxf(st[m][2][r], st[m][3][r]));
          v = fmaxf(v, __shfl_xor(v, 1));
          v = fmaxf(v, __shfl_xor(v, 2));
          v = fmaxf(v, __shfl_xor(v, 4));
          v = fmaxf(v, __shfl_xor(v, 8));
          const float mnew = fmaxf(mrun[m][r], v);
          const float f = __expf(mrun[m][r] - mnew);
          mrun[m][r] = mnew;
          fs[m][r] = f;
          float rs = 0.f;
#pragma unroll
          for (int kvf = 0; kvf < 4; kvf++) {
            st[m][kvf][r] = __expf(st[m][kvf][r] - mnew);
            rs += st[m][kvf][r];
          }
          rs += __shfl_xor(rs, 1);
          rs += __shfl_xor(rs, 2);
          rs += __shfl_xor(rs, 4);
          rs += __shfl_xor(rs, 8);
          lrun[m][r] = lrun[m][r] * f + rs;
        }
#pragma unroll
      for (int m = 0; m < 2; m++)
#pragma unroll
        for (int n = 0; n < 4; n++)
#pragma unroll
          for (int r = 0; r < 4; r++) accO[m][n][r] *= fs[m][r];
      // ---- P -> bf16 -> per-wave LDS (layout convert for A-operand) ----
#pragma unroll
      for (int m = 0; m < 2; m++)
#pragma unroll
        for (int kvf = 0; kvf < 4; kvf++)
#pragma unroll
          for (int r = 0; r < 4; r++)
            Pw[(m * 16 + 4 * lg + r) * 72 + kvf * 16 + lr] = f2b(st[m][kvf][r]);
      // ---- PV: O += P @ V ----
#pragma unroll
      for (int hh = 0; hh < 2; hh++) {
        s8v pf[2];
#pragma unroll
        for (int m = 0; m < 2; m++)
          pf[m] = *(const s8v*)&Pw[(m * 16 + lr) * 72 + hh * 32 + 8 * lg];
#pragma unroll
        for (int n = 0; n < 4; n++) {
          s8v vf = *(const s8v*)&lVt[(n * 16 + lr) * 72 + hh * 32 + 8 * lg];
#pragma unroll
          for (int m = 0; m < 2; m++)
            accO[m][n] = __builtin_amdgcn_mfma_f32_16x16x32_bf16(pf[m], vf, accO[m][n], 0, 0, 0);
        }
      }
    }
  }
  // ---- epilogue: O/l, merge heads into [B][S][H*64] bf16 ----
  const int b = bh >> 4, h = bh & 15;
#pragma unroll
  for (int m = 0; m < 2; m++)
#pragma unroll
    for (int n = 0; n < 4; n++)
#pragma unroll
      for (int r = 0; r < 4; r++) {
        const int qq = qbase + m * 16 + 4 * lg + r;
        const int dh = n * 16 + lr;
        O[(size_t)(b * 2048 + qq) * 1024 + h * 64 + dh] = f2b(accO[m][n][r] / lrun[m][r]);
      }
}

extern "C" void kernel_launch(void* const* d_in, const int* in_sizes, int n_in,
                              void* d_out, int out_size, void* d_ws, size_t ws_size,
                              hipStream_t stream) {
  const float* x      = (const float*)d_in[0];
  const float* w_attn = (const float*)d_in[1];
  const float* b_attn = (const float*)d_in[2];
  const float* w_proj = (const float*)d_in[3];
  const float* b_proj = (const float*)d_in[4];
  float* out = (float*)d_out;

  // workspace (bf16 elements): 72 MB total
  u16* ws  = (u16*)d_ws;
  u16* xb  = ws;                   // x bf16 [8192][1024]; reused as a_buf after QKV GEMM
  u16* wTa = xb + 8388608;         // w_attn^T bf16 [3072][1024]
  u16* wTp = wTa + 3145728;        // w_proj^T bf16 [1024][1024]
  u16* qb  = wTp + 1048576;        // [64 bh][2048][64], pre-scaled by 0.125
  u16* kb  = qb + 8388608;
  u16* vb  = kb + 8388608;

  k_cvt<<<8192, 256, 0, stream>>>(x, xb, 2097152);
  k_tr<<<dim3(96, 32), dim3(32, 8), 0, stream>>>(w_attn, wTa, 1024, 3072);
  k_tr<<<dim3(32, 32), dim3(32, 8), 0, stream>>>(w_proj, wTp, 1024, 1024);
  k_gemm<0><<<dim3(24, 64), 256, 0, stream>>>(xb, wTa, b_attn, qb, kb, vb, nullptr, 8192, 3072, 1024);
  k_attn<<<dim3(64, 16), 256, 0, stream>>>(qb, kb, vb, xb);
  k_gemm<1><<<dim3(8, 64), 256, 0, stream>>>(xb, wTp, b_proj, nullptr, nullptr, nullptr, out, 8192, 1024, 1024);
}

// Round 2
// 210.758 us; speedup vs baseline: 1.1766x; 1.1766x over previous
//
#include <hip/hip_runtime.h>

// GPT-2 attention block, B=4 S=2048 D=1024 H=16 DH=64, f32 in/out.
// bf16 MFMA (v_mfma_f32_16x16x32_bf16), f32 accumulate.
// Fragment layouts (gfx950, verified round 1):
//   A: lane l elem e -> A[l&15][8*(l>>4)+e]
//   B: lane l elem e -> B[l&15][8*(l>>4)+e]   (col-indexed)
//   C/D: lane l reg r -> D[4*(l>>4)+r][l&15]

typedef short  s8v   __attribute__((ext_vector_type(8)));  // 8 bf16 (16B)
typedef float  f32x4 __attribute__((ext_vector_type(4)));
typedef unsigned short u16;
typedef u16    u16x4 __attribute__((ext_vector_type(4)));
typedef unsigned int u32;
typedef u32    u32x2 __attribute__((ext_vector_type(2)));

__device__ __forceinline__ u16 f2b(float f) {
  union { float f; unsigned u; } v; v.f = f;
  unsigned r = v.u + 0x7FFFu + ((v.u >> 16) & 1u);   // RNE
  return (u16)(r >> 16);
}
__device__ __forceinline__ u32 cvtpk(float lo, float hi) {   // bf16(lo) | bf16(hi)<<16
  u32 r; asm("v_cvt_pk_bf16_f32 %0, %1, %2" : "=v"(r) : "v"(lo), "v"(hi)); return r;
}

#define QSCALE 0.18033688011112042f   // 0.125 * log2(e): softmax done in exp2 domain

// ---------------- f32 -> bf16 elementwise ----------------
__global__ __launch_bounds__(256) void k_cvt(const float* __restrict__ in,
                                             u16* __restrict__ out, int n4) {
  int t = blockIdx.x * 256 + threadIdx.x;
  if (t < n4) {
    f32x4 f = ((const f32x4*)in)[t];
    u16x4 o;
    o[0] = f2b(f[0]); o[1] = f2b(f[1]); o[2] = f2b(f[2]); o[3] = f2b(f[3]);
    ((u16x4*)out)[t] = o;
  }
}

// ---------------- f32 [R][C] -> bf16 [C][R] transpose ----------------
__global__ __launch_bounds__(256) void k_tr(const float* __restrict__ in,
                                            u16* __restrict__ out, int R, int C) {
  __shared__ float tile[32][33];
  int c0 = blockIdx.x * 32, r0 = blockIdx.y * 32;
  int tx = threadIdx.x, ty = threadIdx.y;
#pragma unroll
  for (int j = 0; j < 4; j++)
    tile[ty + j * 8][tx] = in[(size_t)(r0 + ty + j * 8) * C + c0 + tx];
  __syncthreads();
#pragma unroll
  for (int j = 0; j < 4; j++)
    out[(size_t)(c0 + ty + j * 8) * R + r0 + tx] = f2b(tile[tx][ty + j * 8]);
}

// ---------------- bf16 GEMM: C[M,N] = A[M,K] @ Bt[N,K]^T (+bias) ----------------
// EPI 0: scatter to q/k [bh][S][64] (q pre-scaled), v TRANSPOSED [bh][64][S].
// EPI 1: f32 out.
template <int EPI>
__global__ __launch_bounds__(256) void k_gemm(
    const u16* __restrict__ A, const u16* __restrict__ Bt,
    const float* __restrict__ bias,
    u16* __restrict__ qb, u16* __restrict__ kb, u16* __restrict__ vb,
    float* __restrict__ outf, int M, int N, int K) {
  __shared__ u16 lA[128 * 40];
  __shared__ u16 lB[128 * 40];
  const int tid = threadIdx.x;
  const int lane = tid & 63, w = tid >> 6;
  const int wr = (w >> 1) * 64, wc = (w & 1) * 64;
  const int lr = lane & 15, lg = lane >> 4;
  const int m0 = blockIdx.y * 128, n0 = blockIdx.x * 128;

  const int srow = tid >> 1, scol = (tid & 1) * 16;
  const u16* gA = A + (size_t)(m0 + srow) * K + scol;
  const u16* gB = Bt + (size_t)(n0 + srow) * K + scol;

  f32x4 acc[4][4];
  f32x4 zz = {0.f, 0.f, 0.f, 0.f};
#pragma unroll
  for (int m = 0; m < 4; m++)
#pragma unroll
    for (int n = 0; n < 4; n++) acc[m][n] = zz;

  s8v a0 = *(const s8v*)(gA), a1 = *(const s8v*)(gA + 8);
  s8v b0 = *(const s8v*)(gB), b1 = *(const s8v*)(gB + 8);

  const int nk = K / 32;
  for (int kt = 0; kt < nk; ++kt) {
    __syncthreads();
    *(s8v*)&lA[srow * 40 + scol] = a0;
    *(s8v*)&lA[srow * 40 + scol + 8] = a1;
    *(s8v*)&lB[srow * 40 + scol] = b0;
    *(s8v*)&lB[srow * 40 + scol + 8] = b1;
    if (kt + 1 < nk) {
      const u16* nA = gA + (kt + 1) * 32;
      const u16* nB = gB + (kt + 1) * 32;
      a0 = *(const s8v*)(nA); a1 = *(const s8v*)(nA + 8);
      b0 = *(const s8v*)(nB); b1 = *(const s8v*)(nB + 8);
    }
    __syncthreads();
    s8v af[4], bf[4];
#pragma unroll
    for (int m = 0; m < 4; m++)
      af[m] = *(const s8v*)&lA[(wr + m * 16 + lr) * 40 + 8 * lg];
#pragma unroll
    for (int n = 0; n < 4; n++)
      bf[n] = *(const s8v*)&lB[(wc + n * 16 + lr) * 40 + 8 * lg];
#pragma unroll
    for (int m = 0; m < 4; m++)
#pragma unroll
      for (int n = 0; n < 4; n++)
        acc[m][n] = __builtin_amdgcn_mfma_f32_16x16x32_bf16(af[m], bf[n], acc[m][n], 0, 0, 0);
  }

#pragma unroll
  for (int m = 0; m < 4; m++) {
#pragma unroll
    for (int n = 0; n < 4; n++) {
      const int col = n0 + wc + n * 16 + lr;
      const float bb = bias[col];
      const int row0 = m0 + wr + m * 16 + 4 * lg;
      if (EPI == 0) {
        const int which = col >> 10, d = col & 1023, h = d >> 6, dh = d & 63;
        if (which == 2) {
          // V: transposed layout [bh][dh][S], vectorized 8B store (s consecutive)
          const int b = row0 >> 11, s = row0 & 2047;
          u16x4 ov;
#pragma unroll
          for (int r = 0; r < 4; r++) ov[r] = f2b(acc[m][n][r] + bb);
          *(u16x4*)(vb + ((size_t)((b * 16 + h) * 64 + dh)) * 2048 + s) = ov;
        } else {
          u16* dst = which == 0 ? qb : kb;
          const float sc = which == 0 ? QSCALE : 1.0f;
#pragma unroll
          for (int r = 0; r < 4; r++) {
            const int row = row0 + r;
            const int b = row >> 11, s = row & 2047;
            dst[(size_t)((b * 16 + h) * 2048 + s) * 64 + dh] = f2b((acc[m][n][r] + bb) * sc);
          }
        }
      } else {
#pragma unroll
        for (int r = 0; r < 4; r++)
          outf[(size_t)(row0 + r) * N + col] = acc[m][n][r] + bb;
      }
    }
  }
}

// ---------------- flash attention, causal, swapped-operand bf16 MFMA ----------------
// 512 blocks, each: 4 waves x 32 q-rows = QT 128, TWO qt values (j, 15-j) -> 34 KV
// tiles per block (perfectly balanced). XCD swizzle: all 8 blocks of a bh share an XCD.
__global__ __launch_bounds__(256) void k_attn(
    const u16* __restrict__ Q, const u16* __restrict__ K,
    const u16* __restrict__ Vt, u16* __restrict__ O) {
  __shared__ u16 lK[64 * 72];        // K tile [kv][dh]
  __shared__ u16 lV[64 * 72];        // Vt tile [dh][kv]
  __shared__ u16 lP[4 * 32 * 72];    // per-wave P [q][kv]
  const int lin = blockIdx.x;
  const int bh = ((lin & 7) << 3) | (lin >> 6);   // lin%8 == bh>>3 -> bh-group per XCD
  const int pair = (lin >> 3) & 7;
  const int tid = threadIdx.x, lane = tid & 63, w = tid >> 6;
  const int lr = lane & 15, lg = lane >> 4;
  const int sr = tid >> 2, sc = (tid & 3) * 16;
  u16* Pw = &lP[w * (32 * 72)];
  const u16* Kb = K + (size_t)bh * 2048 * 64;
  const u16* Vb = Vt + (size_t)bh * 64 * 2048;
  const int b_ = bh >> 4, h_ = bh & 15;

  s8v k0, k1, v0, v1;
  auto pref = [&](int kv0) {
    const u16* gk = Kb + (size_t)(kv0 + sr) * 64 + sc;
    const u16* gv = Vb + (size_t)sr * 2048 + kv0 + sc;
    k0 = *(const s8v*)gk; k1 = *(const s8v*)(gk + 8);
    v0 = *(const s8v*)gv; v1 = *(const s8v*)(gv + 8);
  };
  pref(0);

  for (int half = 0; half < 2; ++half) {
    const int qt = half == 0 ? pair : 15 - pair;
    const int qbase = qt * 128 + w * 32;
    s8v qf[2][2];
#pragma unroll
    for (int b = 0; b < 2; b++)
#pragma unroll
      for (int h = 0; h < 2; h++)
        qf[b][h] = *(const s8v*)(Q + (size_t)(bh * 2048 + qbase + b * 16 + lr) * 64 + h * 32 + 8 * lg);

    f32x4 accO[4][2];
    f32x4 zz = {0.f, 0.f, 0.f, 0.f};
#pragma unroll
    for (int a = 0; a < 4; a++) { accO[a][0] = zz; accO[a][1] = zz; }
    float mrun[2] = {-1e30f, -1e30f}, lrun[2] = {0.f, 0.f};

    const int ntile = 2 * qt + 2;
    for (int kvt = 0; kvt < ntile; ++kvt) {
      const int kv0 = kvt * 64;
      __syncthreads();                       // prior compute done with lK/lV
      *(s8v*)&lK[sr * 72 + sc] = k0;
      *(s8v*)&lK[sr * 72 + sc + 8] = k1;
      *(s8v*)&lV[sr * 72 + sc] = v0;
      *(s8v*)&lV[sr * 72 + sc + 8] = v1;
      if (kvt + 1 < ntile) pref((kvt + 1) * 64);      // hide HBM under compute
      else if (half == 0) pref(0);                    // first tile of second qt
      __syncthreads();

      if (kv0 <= qbase + 31) {               // wave-uniform causal skip
        // ---- swapped QK^T: St[kv][q], q = lane-local column ----
        f32x4 st[4][2];
#pragma unroll
        for (int a = 0; a < 4; a++) {
          s8v af0 = *(const s8v*)&lK[(a * 16 + lr) * 72 + 8 * lg];
          s8v af1 = *(const s8v*)&lK[(a * 16 + lr) * 72 + 32 + 8 * lg];
#pragma unroll
          for (int b = 0; b < 2; b++) {
            f32x4 z = {0.f, 0.f, 0.f, 0.f};
            z = __builtin_amdgcn_mfma_f32_16x16x32_bf16(af0, qf[b][0], z, 0, 0, 0);
            st[a][b] = __builtin_amdgcn_mfma_f32_16x16x32_bf16(af1, qf[b][1], z, 0, 0, 0);
          }
        }
        // ---- causal mask (diagonal tiles only) ----
        if (kv0 + 63 > qbase) {
#pragma unroll
          for (int a = 0; a < 4; a++)
#pragma unroll
            for (int b = 0; b < 2; b++)
#pragma unroll
              for (int r = 0; r < 4; r++) {
                const int kk = kv0 + a * 16 + 4 * lg + r;
                const int qq = qbase + b * 16 + lr;
                if (kk > qq) st[a][b][r] = -1e30f;
              }
        }
        // ---- online softmax: per-thread q column, 2 shuffles per reduce ----
        float fs[2];
#pragma unroll
        for (int b = 0; b < 2; b++) {
          float mx = st[0][b][0];
#pragma unroll
          for (int a = 0; a < 4; a++)
#pragma unroll
            for (int r = 0; r < 4; r++) mx = fmaxf(mx, st[a][b][r]);
          mx = fmaxf(mx, __shfl_xor(mx, 16));
          mx = fmaxf(mx, __shfl_xor(mx, 32));
          const float mnew = fmaxf(mrun[b], mx);
          const float f = exp2f(mrun[b] - mnew);
          float s = 0.f;
#pragma unroll
          for (int a = 0; a < 4; a++)
#pragma unroll
            for (int r = 0; r < 4; r++) {
              const float e = exp2f(st[a][b][r] - mnew);
              st[a][b][r] = e; s += e;
            }
          s += __shfl_xor(s, 16);
          s += __shfl_xor(s, 32);
          lrun[b] = lrun[b] * f + s;
          mrun[b] = mnew; fs[b] = f;
        }
#pragma unroll
        for (int a = 0; a < 4; a++)
#pragma unroll
          for (int b = 0; b < 2; b++)
#pragma unroll
            for (int r = 0; r < 4; r++) accO[a][b][r] *= fs[b];
        // ---- P -> bf16 (cvt_pk) -> per-wave LDS, vectorized 8B stores ----
#pragma unroll
        for (int b = 0; b < 2; b++)
#pragma unroll
          for (int a = 0; a < 4; a++) {
            u32x2 pk;
            pk[0] = cvtpk(st[a][b][0], st[a][b][1]);
            pk[1] = cvtpk(st[a][b][2], st[a][b][3]);
            *(u32x2*)&Pw[(b * 16 + lr) * 72 + a * 16 + 4 * lg] = pk;
          }
        // ---- swapped PV: O^T[dh][q] += Vt @ P^T ----
#pragma unroll
        for (int ap = 0; ap < 2; ap++) {
          s8v pf0 = *(const s8v*)&Pw[lr * 72 + ap * 32 + 8 * lg];
          s8v pf1 = *(const s8v*)&Pw[(16 + lr) * 72 + ap * 32 + 8 * lg];
#pragma unroll
          for (int a = 0; a < 4; a++) {
            s8v vf = *(const s8v*)&lV[(a * 16 + lr) * 72 + ap * 32 + 8 * lg];
            accO[a][0] = __builtin_amdgcn_mfma_f32_16x16x32_bf16(vf, pf0, accO[a][0], 0, 0, 0);
            accO[a][1] = __builtin_amdgcn_mfma_f32_16x16x32_bf16(vf, pf1, accO[a][1], 0, 0, 0);
          }
        }
      }
    }
    // ---- epilogue: O = (O^T)/l, merge heads, vectorized 8B stores ----
#pragma unroll
    for (int b = 0; b < 2; b++) {
      const float rinv = 1.0f / lrun[b];
      const int qq = qbase + b * 16 + lr;
#pragma unroll
      for (int a = 0; a < 4; a++) {
        u32x2 o;
        o[0] = cvtpk(accO[a][b][0] * rinv, accO[a][b][1] * rinv);
        o[1] = cvtpk(accO[a][b][2] * rinv, accO[a][b][3] * rinv);
        *(u32x2*)(O + (size_t)(b_ * 2048 + qq) * 1024 + h_ * 64 + a * 16 + 4 * lg) = o;
      }
    }
  }
}

extern "C" void kernel_launch(void* const* d_in, const int* in_sizes, int n_in,
                              void* d_out, int out_size, void* d_ws, size_t ws_size,
                              hipStream_t stream) {
  const float* x      = (const float*)d_in[0];
  const float* w_attn = (const float*)d_in[1];
  const float* b_attn = (const float*)d_in[2];
  const float* w_proj = (const float*)d_in[3];
  const float* b_proj = (const float*)d_in[4];
  float* out = (float*)d_out;

  u16* ws  = (u16*)d_ws;
  u16* xb  = ws;                   // x bf16 [8192][1024]; reused as attn-out after QKV GEMM
  u16* wTa = xb + 8388608;         // w_attn^T bf16 [3072][1024]
  u16* wTp = wTa + 3145728;        // w_proj^T bf16 [1024][1024]
  u16* qb  = wTp + 1048576;        // [64 bh][2048][64], pre-scaled by 0.125*log2e
  u16* kb  = qb + 8388608;         // [64 bh][2048][64]
  u16* vb  = kb + 8388608;         // [64 bh][64][2048]  (transposed)

  k_cvt<<<8192, 256, 0, stream>>>(x, xb, 2097152);
  k_tr<<<dim3(96, 32), dim3(32, 8), 0, stream>>>(w_attn, wTa, 1024, 3072);
  k_tr<<<dim3(32, 32), dim3(32, 8), 0, stream>>>(w_proj, wTp, 1024, 1024);
  k_gemm<0><<<dim3(24, 64), 256, 0, stream>>>(xb, wTa, b_attn, qb, kb, vb, nullptr, 8192, 3072, 1024);
  k_attn<<<512, 256, 0, stream>>>(qb, kb, vb, xb);
  k_gemm<1><<<dim3(8, 64), 256, 0, stream>>>(xb, wTp, b_proj, nullptr, nullptr, nullptr, out, 8192, 1024, 1024);
}

// Round 3
// 195.541 us; speedup vs baseline: 1.2681x; 1.0778x over previous
//
#include <hip/hip_runtime.h>

// GPT-2 attention block, B=4 S=2048 D=1024 H=16 DH=64, f32 in/out.
// GEMMs: 16x16x32 bf16 MFMA, global_load_lds staging (m97 structure).
// Attention: 32x32x16 bf16 MFMA, swapped operands, in-register softmax
//   (cvt_pk_bf16 + v_permlane32_swap), double-buffered XOR-swizzled LDS.
// Layouts (gfx950):
//   16x16x32: A[l&15][8*(l>>4)+e], B[l&15][8*(l>>4)+e], D[4*(l>>4)+r][l&15]
//   32x32x16: A[l&31][8*(l>>5)+e], B[l&31][8*(l>>5)+e],
//             D[(r&3)+8*(r>>2)+4*(l>>5)][l&31]   (verified m74/m101)

typedef short  s8v   __attribute__((ext_vector_type(8)));  // 8 bf16 (16B)
typedef float  f32x4 __attribute__((ext_vector_type(4)));
typedef float  f32x16 __attribute__((ext_vector_type(16)));
typedef unsigned short u16;
typedef u16    u16x4 __attribute__((ext_vector_type(4)));
typedef unsigned int u32;
typedef u32    u32x2 __attribute__((ext_vector_type(2)));

__device__ __forceinline__ u16 f2b(float f) {
  union { float f; unsigned u; } v; v.f = f;
  unsigned r = v.u + 0x7FFFu + ((v.u >> 16) & 1u);   // RNE
  return (u16)(r >> 16);
}
__device__ __forceinline__ u32 cvtpk(float lo, float hi) {   // bf16(lo)|bf16(hi)<<16
  u32 r; asm("v_cvt_pk_bf16_f32 %0, %1, %2" : "=v"(r) : "v"(lo), "v"(hi)); return r;
}
// d.hi_lanes <-> s.lo_lanes: after, d = {d.lo, s.lo_old}, s = {d.hi_old, s.hi}
__device__ __forceinline__ void plswap(u32 &d, u32 &s) {
  asm volatile("v_permlane32_swap_b32 %0, %1" : "+v"(d), "+v"(s));
}
__device__ __forceinline__ void gll16(const void* g, void* l) {
  __builtin_amdgcn_global_load_lds((const __attribute__((address_space(1))) void*)g,
                                   (__attribute__((address_space(3))) void*)l, 16, 0, 0);
}

#define QSCALE 0.18033688011112042f   // 0.125 * log2(e): softmax in exp2 domain

// ---------------- f32 -> bf16 elementwise ----------------
__global__ __launch_bounds__(256) void k_cvt(const float* __restrict__ in,
                                             u16* __restrict__ out, int n4) {
  int t = blockIdx.x * 256 + threadIdx.x;
  if (t < n4) {
    f32x4 f = ((const f32x4*)in)[t];
    u16x4 o;
    o[0] = f2b(f[0]); o[1] = f2b(f[1]); o[2] = f2b(f[2]); o[3] = f2b(f[3]);
    ((u16x4*)out)[t] = o;
  }
}

// ---------------- f32 [R][C] -> bf16 [C][R] transpose ----------------
__global__ __launch_bounds__(256) void k_tr(const float* __restrict__ in,
                                            u16* __restrict__ out, int R, int C) {
  __shared__ float tile[32][33];
  int c0 = blockIdx.x * 32, r0 = blockIdx.y * 32;
  int tx = threadIdx.x, ty = threadIdx.y;
#pragma unroll
  for (int j = 0; j < 4; j++)
    tile[ty + j * 8][tx] = in[(size_t)(r0 + ty + j * 8) * C + c0 + tx];
  __syncthreads();
#pragma unroll
  for (int j = 0; j < 4; j++)
    out[(size_t)(c0 + ty + j * 8) * R + r0 + tx] = f2b(tile[tx][ty + j * 8]);
}

// ---------------- bf16 GEMM: C[M,N] = A[M,K] @ Bt[N,K]^T (+bias) ----------------
// 128x128 tile, BK=32, 4 waves, global_load_lds staging, linear [128][32] LDS.
template <int EPI>
__global__ __launch_bounds__(256) void k_gemm(
    const u16* __restrict__ A, const u16* __restrict__ Bt,
    const float* __restrict__ bias,
    u16* __restrict__ qb, u16* __restrict__ kb, u16* __restrict__ vb,
    float* __restrict__ outf, int M, int N, int K) {
  __shared__ u16 lA[128 * 32];
  __shared__ u16 lB[128 * 32];
  const int tid = threadIdx.x;
  const int lane = tid & 63, w = tid >> 6;
  const int wr = (w >> 1) * 64, wc = (w & 1) * 64;
  const int lr = lane & 15, lg = lane >> 4;
  const int m0 = blockIdx.y * 128, n0 = blockIdx.x * 128;

  const int crow = lane >> 2;          // row within 16-row chunk
  const int ccol = (lane & 3) * 8;     // u16 col within 32
  const u16* gA = A + (size_t)(m0 + 32 * w + crow) * K + ccol;
  const u16* gB = Bt + (size_t)(n0 + 32 * w + crow) * K + ccol;

  f32x4 acc[4][4];
  f32x4 zz = {0.f, 0.f, 0.f, 0.f};
#pragma unroll
  for (int m = 0; m < 4; m++)
#pragma unroll
    for (int n = 0; n < 4; n++) acc[m][n] = zz;

  const int nk = K / 32;
  for (int kt = 0; kt < nk; ++kt) {
    gll16(gA + kt * 32, &lA[w * 1024]);
    gll16(gA + kt * 32 + 16 * (size_t)K, &lA[w * 1024 + 512]);
    gll16(gB + kt * 32, &lB[w * 1024]);
    gll16(gB + kt * 32 + 16 * (size_t)K, &lB[w * 1024 + 512]);
    __syncthreads();                       // drains vmcnt -> tiles ready
    s8v af[4], bf[4];
#pragma unroll
    for (int m = 0; m < 4; m++)
      af[m] = *(const s8v*)&lA[(wr + m * 16 + lr) * 32 + 8 * lg];
#pragma unroll
    for (int n = 0; n < 4; n++)
      bf[n] = *(const s8v*)&lB[(wc + n * 16 + lr) * 32 + 8 * lg];
#pragma unroll
    for (int m = 0; m < 4; m++)
#pragma unroll
      for (int n = 0; n < 4; n++)
        acc[m][n] = __builtin_amdgcn_mfma_f32_16x16x32_bf16(af[m], bf[n], acc[m][n], 0, 0, 0);
    __syncthreads();                       // reads done before next overwrite
  }

#pragma unroll
  for (int m = 0; m < 4; m++) {
#pragma unroll
    for (int n = 0; n < 4; n++) {
      const int col = n0 + wc + n * 16 + lr;
      const float bb = bias[col];
      const int row0 = m0 + wr + m * 16 + 4 * lg;
      if (EPI == 0) {
        const int which = col >> 10, d = col & 1023, h = d >> 6, dh = d & 63;
        if (which == 2) {
          const int b = row0 >> 11, s = row0 & 2047;
          u16x4 ov;
#pragma unroll
          for (int r = 0; r < 4; r++) ov[r] = f2b(acc[m][n][r] + bb);
          *(u16x4*)(vb + ((size_t)((b * 16 + h) * 64 + dh)) * 2048 + s) = ov;
        } else {
          u16* dst = which == 0 ? qb : kb;
          const float sc = which == 0 ? QSCALE : 1.0f;
#pragma unroll
          for (int r = 0; r < 4; r++) {
            const int row = row0 + r;
            const int b = row >> 11, s = row & 2047;
            dst[(size_t)((b * 16 + h) * 2048 + s) * 64 + dh] = f2b((acc[m][n][r] + bb) * sc);
          }
        }
      } else {
#pragma unroll
        for (int r = 0; r < 4; r++)
          outf[(size_t)(row0 + r) * N + col] = acc[m][n][r] + bb;
      }
    }
  }
}

// ---------------- flash attention, causal, swapped 32x32 MFMA, in-reg softmax ----
// grid 1024 = (bh,qt), LPT order (big qt first), bh-group per XCD.
// Block: 4 waves x 32 q. KVT=64. LDS: double-buffered K,V in 16B-cell layout
//   cell(slot, r) = slot*64 + (r ^ slot)   (slot = 16B slice of the 128B row)
__global__ __launch_bounds__(256, 3) void k_attn(
    const u16* __restrict__ Q, const u16* __restrict__ K,
    const u16* __restrict__ Vt, u16* __restrict__ O) {
  __shared__ u16 lKV[2][8192];     // [buf][ K: 4096 u16 | V: 4096 u16 ]
  const int x = blockIdx.x;
  const int bh = ((x & 7) << 3) | ((x >> 3) & 7);
  const int qt = 15 - (x >> 6);
  const int tid = threadIdx.x, lane = tid & 63, w = tid >> 6;
  const int l31 = lane & 31, h = lane >> 5;
  const int qbase = qt * 128 + w * 32;
  const u16* Kb = K + (size_t)bh * 2048 * 64;
  const u16* Vb = Vt + (size_t)bh * 64 * 2048;

  const int skv = tid >> 2;          // K: kv row / V: dh row
  const int ssl = (tid & 3) * 2;     // first of two 16B slots

  s8v kR0, kR1, vR0, vR1;
  auto pref = [&](int kv0) {
    const u16* gk = Kb + (size_t)(kv0 + skv) * 64 + ssl * 8;
    const u16* gv = Vb + (size_t)skv * 2048 + kv0 + ssl * 8;
    kR0 = *(const s8v*)gk; kR1 = *(const s8v*)(gk + 8);
    vR0 = *(const s8v*)gv; vR1 = *(const s8v*)(gv + 8);
  };
  auto stage = [&](int buf) {
    u16* base = &lKV[buf][0];
    *(s8v*)&base[(ssl * 64 + (skv ^ ssl)) * 8] = kR0;
    *(s8v*)&base[((ssl + 1) * 64 + (skv ^ (ssl + 1))) * 8] = kR1;
    *(s8v*)&base[4096 + (ssl * 64 + (skv ^ ssl)) * 8] = vR0;
    *(s8v*)&base[4096 + ((ssl + 1) * 64 + (skv ^ (ssl + 1))) * 8] = vR1;
  };

  // Q B-frags: lane l -> q col = l31, k(dh) = ks*16 + 8h + e
  s8v qf[4];
#pragma unroll
  for (int ks = 0; ks < 4; ks++)
    qf[ks] = *(const s8v*)(Q + (size_t)(bh * 2048 + qbase + l31) * 64 + ks * 16 + 8 * h);

  f32x16 accO0, accO1;
#pragma unroll
  for (int i = 0; i < 16; i++) { accO0[i] = 0.f; accO1[i] = 0.f; }
  float mrun = -1e30f, lrun = 0.f;

  const int ntile = 2 * qt + 2;
  pref(0); stage(0);
  if (ntile > 1) pref(64);

  for (int t = 0; t < ntile; ++t) {
    const int kv0 = t * 64;
    __syncthreads();                       // buf[t&1] staged, prior reads done
    const u16* base = &lKV[t & 1][0];

    if (kv0 <= qbase + 31) {               // wave-uniform causal skip
      // ---- swapped QK^T: S^T[kv][q], one q column per lane ----
      f32x16 st0, st1;
#pragma unroll
      for (int i = 0; i < 16; i++) { st0[i] = 0.f; st1[i] = 0.f; }
#pragma unroll
      for (int ks = 0; ks < 4; ks++) {
        const int sl = 2 * ks + h;
        s8v a0 = *(const s8v*)&base[(sl * 64 + (l31 ^ sl)) * 8];
        s8v a1 = *(const s8v*)&base[(sl * 64 + ((32 + l31) ^ sl)) * 8];
        st0 = __builtin_amdgcn_mfma_f32_32x32x16_bf16(a0, qf[ks], st0, 0, 0, 0);
        st1 = __builtin_amdgcn_mfma_f32_32x32x16_bf16(a1, qf[ks], st1, 0, 0, 0);
      }
      // ---- causal mask (diagonal tiles only) ----
      if (kv0 + 63 > qbase) {
        const int dq = qbase + l31 - kv0;  // kv_local <= dq allowed
#pragma unroll
        for (int r = 0; r < 16; r++) {
          const int kl = (r & 3) + 8 * (r >> 2) + 4 * h;
          if (kl > dq) st0[r] = -1e30f;
          if (kl + 32 > dq) st1[r] = -1e30f;
        }
      }
      // ---- online softmax, defer-max (T13) ----
      float mx = st0[0];
#pragma unroll
      for (int r = 1; r < 16; r++) mx = fmaxf(mx, st0[r]);
#pragma unroll
      for (int r = 0; r < 16; r++) mx = fmaxf(mx, st1[r]);
      mx = fmaxf(mx, __shfl_xor(mx, 32));
      if (!__all(mx <= mrun + 11.0f)) {
        const float mnew = fmaxf(mrun, mx);
        const float f = exp2f(mrun - mnew);
        lrun *= f;
#pragma unroll
        for (int r = 0; r < 16; r++) { accO0[r] *= f; accO1[r] *= f; }
        mrun = mnew;
      }
      float s = 0.f;
#pragma unroll
      for (int r = 0; r < 16; r++) { st0[r] = exp2f(st0[r] - mrun); s += st0[r]; }
#pragma unroll
      for (int r = 0; r < 16; r++) { st1[r] = exp2f(st1[r] - mrun); s += st1[r]; }
      s += __shfl_xor(s, 32);
      lrun += s;
      // ---- P -> bf16 in-register: W[kvb][2a+c] = kv pair (8a+4h+2c, +1) ----
      u32 W0[8], W1[8];
#pragma unroll
      for (int a = 0; a < 4; a++) {
        W0[2 * a]     = cvtpk(st0[4 * a], st0[4 * a + 1]);
        W0[2 * a + 1] = cvtpk(st0[4 * a + 2], st0[4 * a + 3]);
        W1[2 * a]     = cvtpk(st1[4 * a], st1[4 * a + 1]);
        W1[2 * a + 1] = cvtpk(st1[4 * a + 2], st1[4 * a + 3]);
      }
      // ---- PV: O^T[dh][q] += Vt @ P, B-frag via permlane32_swap ----
#pragma unroll
      for (int ks = 0; ks < 4; ks++) {
        const int kp = ks & 1;
        u32 x0 = (ks < 2) ? W0[4 * kp]     : W1[4 * kp];
        u32 y0 = (ks < 2) ? W0[4 * kp + 2] : W1[4 * kp + 2];
        u32 x1 = (ks < 2) ? W0[4 * kp + 1] : W1[4 * kp + 1];
        u32 y1 = (ks < 2) ? W0[4 * kp + 3] : W1[4 * kp + 3];
        plswap(x0, y0);   // x0 = {X.lo, Y.lo}, y0 = {X.hi, Y.hi}
        plswap(x1, y1);
        union { u32 u[4]; s8v v; } fb;
        fb.u[0] = x0; fb.u[1] = x1; fb.u[2] = y0; fb.u[3] = y1;
        const int sl = 2 * ks + h;
        s8v va0 = *(const s8v*)&base[4096 + (sl * 64 + (l31 ^ sl)) * 8];
        s8v va1 = *(const s8v*)&base[4096 + (sl * 64 + ((32 + l31) ^ sl)) * 8];
        accO0 = __builtin_amdgcn_mfma_f32_32x32x16_bf16(va0, fb.v, accO0, 0, 0, 0);
        accO1 = __builtin_amdgcn_mfma_f32_32x32x16_bf16(va1, fb.v, accO1, 0, 0, 0);
      }
    }
    if (t + 1 < ntile) {
      stage((t + 1) & 1);                  // waits vmcnt of pref(t+1)
      if (t + 2 < ntile) pref((t + 2) * 64);
    }
  }

  // ---- epilogue: O = O^T / l, merge heads, 8B stores ----
  const int b_ = bh >> 4, h_ = bh & 15;
  const float rinv = 1.0f / lrun;
  u16* Ob = O + (size_t)(b_ * 2048 + qbase + l31) * 1024 + h_ * 64;
#pragma unroll
  for (int a = 0; a < 4; a++) {
    u32x2 o0, o1;
    o0[0] = cvtpk(accO0[4 * a] * rinv, accO0[4 * a + 1] * rinv);
    o0[1] = cvtpk(accO0[4 * a + 2] * rinv, accO0[4 * a + 3] * rinv);
    o1[0] = cvtpk(accO1[4 * a] * rinv, accO1[4 * a + 1] * rinv);
    o1[1] = cvtpk(accO1[4 * a + 2] * rinv, accO1[4 * a + 3] * rinv);
    *(u32x2*)(Ob + 8 * a + 4 * h) = o0;
    *(u32x2*)(Ob + 32 + 8 * a + 4 * h) = o1;
  }
}

extern "C" void kernel_launch(void* const* d_in, const int* in_sizes, int n_in,
                              void* d_out, int out_size, void* d_ws, size_t ws_size,
                              hipStream_t stream) {
  const float* x      = (const float*)d_in[0];
  const float* w_attn = (const float*)d_in[1];
  const float* b_attn = (const float*)d_in[2];
  const float* w_proj = (const float*)d_in[3];
  const float* b_proj = (const float*)d_in[4];
  float* out = (float*)d_out;

  u16* ws  = (u16*)d_ws;
  u16* xb  = ws;                   // x bf16 [8192][1024]; reused as attn-out
  u16* wTa = xb + 8388608;         // w_attn^T bf16 [3072][1024]
  u16* wTp = wTa + 3145728;        // w_proj^T bf16 [1024][1024]
  u16* qb  = wTp + 1048576;        // [64 bh][2048][64], pre-scaled 0.125*log2e
  u16* kb  = qb + 8388608;         // [64 bh][2048][64]
  u16* vb  = kb + 8388608;         // [64 bh][64][2048]  (transposed)

  k_cvt<<<8192, 256, 0, stream>>>(x, xb, 2097152);
  k_tr<<<dim3(96, 32), dim3(32, 8), 0, stream>>>(w_attn, wTa, 1024, 3072);
  k_tr<<<dim3(32, 32), dim3(32, 8), 0, stream>>>(w_proj, wTp, 1024, 1024);
  k_gemm<0><<<dim3(24, 64), 256, 0, stream>>>(xb, wTa, b_attn, qb, kb, vb, nullptr, 8192, 3072, 1024);
  k_attn<<<1024, 256, 0, stream>>>(qb, kb, vb, xb);
  k_gemm<1><<<dim3(8, 64), 256, 0, stream>>>(xb, wTp, b_proj, nullptr, nullptr, nullptr, out, 8192, 1024, 1024);
}

// Round 4
// 182.638 us; speedup vs baseline: 1.3577x; 1.0706x over previous
//
#include <hip/hip_runtime.h>

// GPT-2 attention block, B=4 S=2048 D=1024 H=16 DH=64, f32 in/out.
// GEMMs: 16x16x32 bf16 MFMA, 128x128 tile, 3-buffer counted-vmcnt pipeline,
//        global_load_lds with source-side XOR swizzle (conflict-free ds_read).
// Attention: 32x32x16 bf16 MFMA, swapped operands, in-register softmax,
//        raw-barrier loop (prefetch stays in flight across barriers).
// Layouts (gfx950):
//   16x16x32: A[l&15][8*(l>>4)+e], B[l&15][8*(l>>4)+e], D[4*(l>>4)+r][l&15]
//   32x32x16: A[l&31][8*(l>>5)+e], B[l&31][8*(l>>5)+e],
//             D[(r&3)+8*(r>>2)+4*(l>>5)][l&31]

typedef short  s8v   __attribute__((ext_vector_type(8)));  // 8 bf16 (16B)
typedef float  f32x4 __attribute__((ext_vector_type(4)));
typedef float  f32x16 __attribute__((ext_vector_type(16)));
typedef unsigned short u16;
typedef u16    u16x4 __attribute__((ext_vector_type(4)));
typedef unsigned int u32;
typedef u32    u32x2 __attribute__((ext_vector_type(2)));

__device__ __forceinline__ u16 f2b(float f) {
  union { float f; unsigned u; } v; v.f = f;
  unsigned r = v.u + 0x7FFFu + ((v.u >> 16) & 1u);   // RNE
  return (u16)(r >> 16);
}
__device__ __forceinline__ u32 cvtpk(float lo, float hi) {   // bf16(lo)|bf16(hi)<<16
  u32 r; asm("v_cvt_pk_bf16_f32 %0, %1, %2" : "=v"(r) : "v"(lo), "v"(hi)); return r;
}
__device__ __forceinline__ void plswap(u32 &d, u32 &s) {
  asm volatile("v_permlane32_swap_b32 %0, %1" : "+v"(d), "+v"(s));
}
__device__ __forceinline__ void gll16(const void* g, void* l) {
  __builtin_amdgcn_global_load_lds((const __attribute__((address_space(1))) void*)g,
                                   (__attribute__((address_space(3))) void*)l, 16, 0, 0);
}

#define QSCALE 0.18033688011112042f   // 0.125 * log2(e): softmax in exp2 domain

// ---------------- f32 -> bf16 elementwise ----------------
__global__ __launch_bounds__(256) void k_cvt(const float* __restrict__ in,
                                             u16* __restrict__ out, int n4) {
  int t = blockIdx.x * 256 + threadIdx.x;
  if (t < n4) {
    f32x4 f = ((const f32x4*)in)[t];
    u16x4 o;
    o[0] = f2b(f[0]); o[1] = f2b(f[1]); o[2] = f2b(f[2]); o[3] = f2b(f[3]);
    ((u16x4*)out)[t] = o;
  }
}

// ---------------- f32 [R][C] -> bf16 [C][R] transpose ----------------
__global__ __launch_bounds__(256) void k_tr(const float* __restrict__ in,
                                            u16* __restrict__ out, int R, int C) {
  __shared__ float tile[32][33];
  int c0 = blockIdx.x * 32, r0 = blockIdx.y * 32;
  int tx = threadIdx.x, ty = threadIdx.y;
#pragma unroll
  for (int j = 0; j < 4; j++)
    tile[ty + j * 8][tx] = in[(size_t)(r0 + ty + j * 8) * C + c0 + tx];
  __syncthreads();
#pragma unroll
  for (int j = 0; j < 4; j++)
    out[(size_t)(c0 + ty + j * 8) * R + r0 + tx] = f2b(tile[tx][ty + j * 8]);
}

// ---- one K-tile of MFMA work: 8 swizzled ds_read_b128 + 16 MFMA (setprio'd) ----
__device__ __forceinline__ void gemm_tile(const u16* bA, const u16* bB,
                                          f32x4 (&acc)[4][4],
                                          int wr, int wc, int lr, int lg) {
  s8v af[4], bfr[4];
#pragma unroll
  for (int m = 0; m < 4; m++) {
    const int row = wr + m * 16 + lr;
    af[m] = *(const s8v*)&bA[row * 32 + (lg ^ ((row >> 1) & 3)) * 8];
  }
#pragma unroll
  for (int n = 0; n < 4; n++) {
    const int row = wc + n * 16 + lr;
    bfr[n] = *(const s8v*)&bB[row * 32 + (lg ^ ((row >> 1) & 3)) * 8];
  }
  __builtin_amdgcn_s_setprio(1);
#pragma unroll
  for (int m = 0; m < 4; m++)
#pragma unroll
    for (int n = 0; n < 4; n++)
      acc[m][n] = __builtin_amdgcn_mfma_f32_16x16x32_bf16(af[m], bfr[n], acc[m][n], 0, 0, 0);
  __builtin_amdgcn_s_setprio(0);
}

// ---------------- bf16 GEMM: C[M,N] = A[M,K] @ Bt[N,K]^T (+bias) ----------------
// 128x128 tile, BK=32, 4 waves. 3 LDS buffers, 1 raw barrier + counted vmcnt
// per tile (2-tile prefetch lookahead). Source-swizzled gll staging.
template <int EPI>
__global__ __launch_bounds__(256, 3) void k_gemm(
    const u16* __restrict__ A, const u16* __restrict__ Bt,
    const float* __restrict__ bias,
    u16* __restrict__ qb, u16* __restrict__ kb, u16* __restrict__ vb,
    float* __restrict__ outf, int M, int N, int K) {
  __shared__ u16 lA[3][4096];     // [buf][128 rows][32 cols], 16B-cell swizzled
  __shared__ u16 lB[3][4096];
  const int tid = threadIdx.x;
  const int lane = tid & 63, w = tid >> 6;
  const int wr = (w >> 1) * 64, wc = (w & 1) * 64;
  const int lr = lane & 15, lg = lane >> 4;

  // XCD-chunked block swizzle (grid.x*grid.y % 8 == 0 for both shapes)
  const int nwg = gridDim.x * gridDim.y;
  const int bid = blockIdx.y * gridDim.x + blockIdx.x;
  const int swz = (bid & 7) * (nwg >> 3) + (bid >> 3);
  const int m0 = (swz / gridDim.x) * 128, n0 = (swz % gridDim.x) * 128;

  // staging geometry: sweep sg=2w+s covers LDS cells [64*sg, +64); lane l holds
  // global (row = 16*sg + l/4, cell c = (l&3)^((l>>3)&3))  [inverse of read swz]
  const int rr = lane >> 2;
  const int cb = ((lane & 3) ^ ((lane >> 3) & 3)) * 16;    // byte col in 64B row
  const size_t K2 = (size_t)K * 2;
  const char* gAc = (const char*)A + (size_t)m0 * K2;
  const char* gBc = (const char*)Bt + (size_t)n0 * K2;

  auto stage = [&](int kt, int buf) {
    const size_t ko = (size_t)kt * 64 + cb;
    char* dA = (char*)&lA[buf][0];
    char* dB = (char*)&lB[buf][0];
    gll16(gAc + (size_t)(32 * w + rr) * K2 + ko,      dA + (2 * w) * 1024);
    gll16(gAc + (size_t)(32 * w + 16 + rr) * K2 + ko, dA + (2 * w + 1) * 1024);
    gll16(gBc + (size_t)(32 * w + rr) * K2 + ko,      dB + (2 * w) * 1024);
    gll16(gBc + (size_t)(32 * w + 16 + rr) * K2 + ko, dB + (2 * w + 1) * 1024);
  };

  f32x4 acc[4][4];
  f32x4 zz = {0.f, 0.f, 0.f, 0.f};
#pragma unroll
  for (int m = 0; m < 4; m++)
#pragma unroll
    for (int n = 0; n < 4; n++) acc[m][n] = zz;

  const int nk = K / 32;
  stage(0, 0);
  if (nk > 1) stage(1, 1);

#define STEP(T, CB, SB)                                                     \
  if ((T) < nk) {                                                           \
    if ((T) + 1 < nk) { asm volatile("s_waitcnt vmcnt(4)" ::: "memory"); }  \
    else              { asm volatile("s_waitcnt vmcnt(0)" ::: "memory"); }  \
    __builtin_amdgcn_s_barrier();                                           \
    __builtin_amdgcn_sched_barrier(0);                                      \
    if ((T) + 2 < nk) stage((T) + 2, (SB));                                 \
    gemm_tile(&lA[(CB)][0], &lB[(CB)][0], acc, wr, wc, lr, lg);             \
  }

  for (int t0 = 0; t0 < nk; t0 += 3) {
    STEP(t0,     0, 2)
    STEP(t0 + 1, 1, 0)
    STEP(t0 + 2, 2, 1)
  }
#undef STEP

#pragma unroll
  for (int m = 0; m < 4; m++) {
#pragma unroll
    for (int n = 0; n < 4; n++) {
      const int col = n0 + wc + n * 16 + lr;
      const float bb = bias[col];
      const int row0 = m0 + wr + m * 16 + 4 * lg;
      if (EPI == 0) {
        const int which = col >> 10, d = col & 1023, h = d >> 6, dh = d & 63;
        if (which == 2) {
          const int b = row0 >> 11, s = row0 & 2047;
          u16x4 ov;
#pragma unroll
          for (int r = 0; r < 4; r++) ov[r] = f2b(acc[m][n][r] + bb);
          *(u16x4*)(vb + ((size_t)((b * 16 + h) * 64 + dh)) * 2048 + s) = ov;
        } else {
          u16* dst = which == 0 ? qb : kb;
          const float sc = which == 0 ? QSCALE : 1.0f;
#pragma unroll
          for (int r = 0; r < 4; r++) {
            const int row = row0 + r;
            const int b = row >> 11, s = row & 2047;
            dst[(size_t)((b * 16 + h) * 2048 + s) * 64 + dh] = f2b((acc[m][n][r] + bb) * sc);
          }
        }
      } else {
#pragma unroll
        for (int r = 0; r < 4; r++)
          outf[(size_t)(row0 + r) * N + col] = acc[m][n][r] + bb;
      }
    }
  }
}

// ---------------- flash attention, causal, swapped 32x32 MFMA, in-reg softmax ----
__global__ __launch_bounds__(256, 3) void k_attn(
    const u16* __restrict__ Q, const u16* __restrict__ K,
    const u16* __restrict__ Vt, u16* __restrict__ O) {
  __shared__ u16 lKV[2][8192];     // [buf][ K: 4096 u16 | V: 4096 u16 ]
  const int x = blockIdx.x;
  const int bh = ((x & 7) << 3) | ((x >> 3) & 7);
  const int qt = 15 - (x >> 6);
  const int tid = threadIdx.x, lane = tid & 63, w = tid >> 6;
  const int l31 = lane & 31, h = lane >> 5;
  const int qbase = qt * 128 + w * 32;
  const u16* Kb = K + (size_t)bh * 2048 * 64;
  const u16* Vb = Vt + (size_t)bh * 64 * 2048;

  const int skv = tid >> 2;          // K: kv row / V: dh row
  const int ssl = (tid & 3) * 2;     // first of two 16B slots

  s8v kR0, kR1, vR0, vR1;
  auto pref = [&](int kv0) {
    const u16* gk = Kb + (size_t)(kv0 + skv) * 64 + ssl * 8;
    const u16* gv = Vb + (size_t)skv * 2048 + kv0 + ssl * 8;
    kR0 = *(const s8v*)gk; kR1 = *(const s8v*)(gk + 8);
    vR0 = *(const s8v*)gv; vR1 = *(const s8v*)(gv + 8);
  };
  auto stage = [&](int buf) {
    u16* base = &lKV[buf][0];
    *(s8v*)&base[(ssl * 64 + (skv ^ ssl)) * 8] = kR0;
    *(s8v*)&base[((ssl + 1) * 64 + (skv ^ (ssl + 1))) * 8] = kR1;
    *(s8v*)&base[4096 + (ssl * 64 + (skv ^ ssl)) * 8] = vR0;
    *(s8v*)&base[4096 + ((ssl + 1) * 64 + (skv ^ (ssl + 1))) * 8] = vR1;
  };

  // Q B-frags: lane l -> q col = l31, k(dh) = ks*16 + 8h + e
  s8v qf[4];
#pragma unroll
  for (int ks = 0; ks < 4; ks++)
    qf[ks] = *(const s8v*)(Q + (size_t)(bh * 2048 + qbase + l31) * 64 + ks * 16 + 8 * h);

  f32x16 accO0, accO1;
#pragma unroll
  for (int i = 0; i < 16; i++) { accO0[i] = 0.f; accO1[i] = 0.f; }
  float mrun = -1e30f, lrun = 0.f;

  const int ntile = 2 * qt + 2;
  pref(0); stage(0);
  if (ntile > 1) pref(64);

  for (int t = 0; t < ntile; ++t) {
    const int kv0 = t * 64;
    // raw barrier: drain own ds_writes (lgkm) but leave prefetch loads in flight
    asm volatile("s_waitcnt lgkmcnt(0)" ::: "memory");
    __builtin_amdgcn_s_barrier();
    __builtin_amdgcn_sched_barrier(0);
    const u16* base = &lKV[t & 1][0];

    if (kv0 <= qbase + 31) {               // wave-uniform causal skip
      // ---- swapped QK^T: S^T[kv][q], one q column per lane ----
      f32x16 st0, st1;
#pragma unroll
      for (int i = 0; i < 16; i++) { st0[i] = 0.f; st1[i] = 0.f; }
      __builtin_amdgcn_s_setprio(1);
#pragma unroll
      for (int ks = 0; ks < 4; ks++) {
        const int sl = 2 * ks + h;
        s8v a0 = *(const s8v*)&base[(sl * 64 + (l31 ^ sl)) * 8];
        s8v a1 = *(const s8v*)&base[(sl * 64 + ((32 + l31) ^ sl)) * 8];
        st0 = __builtin_amdgcn_mfma_f32_32x32x16_bf16(a0, qf[ks], st0, 0, 0, 0);
        st1 = __builtin_amdgcn_mfma_f32_32x32x16_bf16(a1, qf[ks], st1, 0, 0, 0);
      }
      __builtin_amdgcn_s_setprio(0);
      // ---- causal mask (diagonal tiles only) ----
      if (kv0 + 63 > qbase) {
        const int dq = qbase + l31 - kv0;  // kv_local <= dq allowed
#pragma unroll
        for (int r = 0; r < 16; r++) {
          const int kl = (r & 3) + 8 * (r >> 2) + 4 * h;
          if (kl > dq) st0[r] = -1e30f;
          if (kl + 32 > dq) st1[r] = -1e30f;
        }
      }
      // ---- online softmax, defer-max (T13) ----
      float mx = st0[0];
#pragma unroll
      for (int r = 1; r < 16; r++) mx = fmaxf(mx, st0[r]);
#pragma unroll
      for (int r = 0; r < 16; r++) mx = fmaxf(mx, st1[r]);
      mx = fmaxf(mx, __shfl_xor(mx, 32));
      if (!__all(mx <= mrun + 11.0f)) {
        const float mnew = fmaxf(mrun, mx);
        const float f = exp2f(mrun - mnew);
        lrun *= f;
#pragma unroll
        for (int r = 0; r < 16; r++) { accO0[r] *= f; accO1[r] *= f; }
        mrun = mnew;
      }
      float s = 0.f;
#pragma unroll
      for (int r = 0; r < 16; r++) { st0[r] = exp2f(st0[r] - mrun); s += st0[r]; }
#pragma unroll
      for (int r = 0; r < 16; r++) { st1[r] = exp2f(st1[r] - mrun); s += st1[r]; }
      s += __shfl_xor(s, 32);
      lrun += s;
      // ---- P -> bf16 in-register ----
      u32 W0[8], W1[8];
#pragma unroll
      for (int a = 0; a < 4; a++) {
        W0[2 * a]     = cvtpk(st0[4 * a], st0[4 * a + 1]);
        W0[2 * a + 1] = cvtpk(st0[4 * a + 2], st0[4 * a + 3]);
        W1[2 * a]     = cvtpk(st1[4 * a], st1[4 * a + 1]);
        W1[2 * a + 1] = cvtpk(st1[4 * a + 2], st1[4 * a + 3]);
      }
      // ---- PV: O^T[dh][q] += Vt @ P, B-frag via permlane32_swap ----
      __builtin_amdgcn_s_setprio(1);
#pragma unroll
      for (int ks = 0; ks < 4; ks++) {
        const int kp = ks & 1;
        u32 x0 = (ks < 2) ? W0[4 * kp]     : W1[4 * kp];
        u32 y0 = (ks < 2) ? W0[4 * kp + 2] : W1[4 * kp + 2];
        u32 x1 = (ks < 2) ? W0[4 * kp + 1] : W1[4 * kp + 1];
        u32 y1 = (ks < 2) ? W0[4 * kp + 3] : W1[4 * kp + 3];
        plswap(x0, y0);
        plswap(x1, y1);
        union { u32 u[4]; s8v v; } fb;
        fb.u[0] = x0; fb.u[1] = x1; fb.u[2] = y0; fb.u[3] = y1;
        const int sl = 2 * ks + h;
        s8v va0 = *(const s8v*)&base[4096 + (sl * 64 + (l31 ^ sl)) * 8];
        s8v va1 = *(const s8v*)&base[4096 + (sl * 64 + ((32 + l31) ^ sl)) * 8];
        accO0 = __builtin_amdgcn_mfma_f32_32x32x16_bf16(va0, fb.v, accO0, 0, 0, 0);
        accO1 = __builtin_amdgcn_mfma_f32_32x32x16_bf16(va1, fb.v, accO1, 0, 0, 0);
      }
      __builtin_amdgcn_s_setprio(0);
    }
    if (t + 1 < ntile) {
      stage((t + 1) & 1);                  // auto vmcnt wait on pref(t+1) regs
      if (t + 2 < ntile) pref((t + 2) * 64);
    }
  }

  // ---- epilogue: O = O^T / l, merge heads, 8B stores ----
  const int b_ = bh >> 4, h_ = bh & 15;
  const float rinv = 1.0f / lrun;
  u16* Ob = O + (size_t)(b_ * 2048 + qbase + l31) * 1024 + h_ * 64;
#pragma unroll
  for (int a = 0; a < 4; a++) {
    u32x2 o0, o1;
    o0[0] = cvtpk(accO0[4 * a] * rinv, accO0[4 * a + 1] * rinv);
    o0[1] = cvtpk(accO0[4 * a + 2] * rinv, accO0[4 * a + 3] * rinv);
    o1[0] = cvtpk(accO1[4 * a] * rinv, accO1[4 * a + 1] * rinv);
    o1[1] = cvtpk(accO1[4 * a + 2] * rinv, accO1[4 * a + 3] * rinv);
    *(u32x2*)(Ob + 8 * a + 4 * h) = o0;
    *(u32x2*)(Ob + 32 + 8 * a + 4 * h) = o1;
  }
}

extern "C" void kernel_launch(void* const* d_in, const int* in_sizes, int n_in,
                              void* d_out, int out_size, void* d_ws, size_t ws_size,
                              hipStream_t stream) {
  const float* x      = (const float*)d_in[0];
  const float* w_attn = (const float*)d_in[1];
  const float* b_attn = (const float*)d_in[2];
  const float* w_proj = (const float*)d_in[3];
  const float* b_proj = (const float*)d_in[4];
  float* out = (float*)d_out;

  u16* ws  = (u16*)d_ws;
  u16* xb  = ws;                   // x bf16 [8192][1024]; reused as attn-out
  u16* wTa = xb + 8388608;         // w_attn^T bf16 [3072][1024]
  u16* wTp = wTa + 3145728;        // w_proj^T bf16 [1024][1024]
  u16* qb  = wTp + 1048576;        // [64 bh][2048][64], pre-scaled 0.125*log2e
  u16* kb  = qb + 8388608;         // [64 bh][2048][64]
  u16* vb  = kb + 8388608;         // [64 bh][64][2048]  (transposed)

  k_cvt<<<8192, 256, 0, stream>>>(x, xb, 2097152);
  k_tr<<<dim3(96, 32), dim3(32, 8), 0, stream>>>(w_attn, wTa, 1024, 3072);
  k_tr<<<dim3(32, 32), dim3(32, 8), 0, stream>>>(w_proj, wTp, 1024, 1024);
  k_gemm<0><<<dim3(24, 64), 256, 0, stream>>>(xb, wTa, b_attn, qb, kb, vb, nullptr, 8192, 3072, 1024);
  k_attn<<<1024, 256, 0, stream>>>(qb, kb, vb, xb);
  k_gemm<1><<<dim3(8, 64), 256, 0, stream>>>(xb, wTp, b_proj, nullptr, nullptr, nullptr, out, 8192, 1024, 1024);
}